// Round 1
// baseline (456.955 us; speedup 1.0000x reference)
//
#include <hip/hip_runtime.h>
#include <stdint.h>

typedef unsigned short u16;
typedef __attribute__((ext_vector_type(8))) short short8;
typedef __attribute__((ext_vector_type(4))) short short4v;
typedef __attribute__((ext_vector_type(4))) float f32x4;

#define NB_  2
#define NT_  2048
#define NC_  2048
#define NH_  16
#define NKV_ 4
#define HD_  128
#define NM_  (NB_*NT_)   // 4096

__device__ __forceinline__ u16 f2b(float x) {
  uint32_t u = __float_as_uint(x);
  u += 0x7fffu + ((u >> 16) & 1u);   // RNE
  return (u16)(u >> 16);
}
__device__ __forceinline__ float b2f(u16 x) {
  return __uint_as_float(((uint32_t)x) << 16);
}

typedef __attribute__((address_space(1))) uint32_t* gp1_t;
typedef __attribute__((address_space(3))) uint32_t* lp3_t;
// async global->LDS, 16B per lane, dest = wave-uniform base + lane*16
__device__ __forceinline__ void async_ld16(const void* g, void* l) {
  __builtin_amdgcn_global_load_lds((gp1_t)(uintptr_t)g, (lp3_t)(uintptr_t)l, 16, 0, 0);
}

// ---------------- fp32 -> bf16 convert ----------------
__global__ void f2bf_kernel(const float* __restrict__ in, u16* __restrict__ out, int n4) {
  int i = blockIdx.x * 256 + threadIdx.x;
  if (i >= n4) return;
  const float4 v = ((const float4*)in)[i];
  short4v o;
  o[0] = (short)f2b(v.x); o[1] = (short)f2b(v.y);
  o[2] = (short)f2b(v.z); o[3] = (short)f2b(v.w);
  *(short4v*)(out + (size_t)i * 4) = o;
}

// ---------------- RoPE + reshape (m, nh*128) -> (B, nh, T, 128) ----------------
__global__ void rope_reshape(const u16* __restrict__ raw, u16* __restrict__ out, int nheads) {
  int tid = blockIdx.x * 256 + threadIdx.x;   // total B*nh*T*64
  int j = tid & 63;
  int t = (tid >> 6) & (NT_ - 1);
  int bh = tid >> 17;                          // 64*2048 = 2^17
  int h = bh % nheads, b = bh / nheads;
  const u16* src = raw + ((size_t)(b * NT_ + t) * nheads + h) * HD_;
  float q0 = b2f(src[j]), q1 = b2f(src[j + 64]);
  float inv = expf(-0.14391156831212787f * (float)j);  // ln(10000)/64
  float ang = (float)t * inv;
  float c = cosf(ang), s = sinf(ang);
  u16* dst = out + ((size_t)(b * nheads + h) * NT_ + t) * HD_;
  dst[j]      = f2b(q0 * c - q1 * s);
  dst[j + 64] = f2b(q1 * c + q0 * s);
}

// ---------------- V transpose: (B*T, KV*128) -> (B, KV, 128, T) ----------------
__global__ void vtrans(const u16* __restrict__ vraw, u16* __restrict__ vt) {
  __shared__ u16 tile[64][72];
  int tt = blockIdx.x, dd = blockIdx.y;
  int tid = threadIdx.x;
  int r = tid >> 3, c8 = (tid & 7) * 8;
#pragma unroll
  for (int it = 0; it < 2; ++it) {
    int row = r + it * 32;
    short8 v = *(const short8*)(vraw + (size_t)(tt * 64 + row) * (NKV_ * HD_) + dd * 64 + c8);
    *(short8*)(&tile[row][c8]) = v;
  }
  __syncthreads();
  int b = (tt * 64) >> 11, t0 = (tt * 64) & (NT_ - 1);
  int dl = tid >> 3, t8 = (tid & 7) * 8;
#pragma unroll
  for (int it = 0; it < 2; ++it) {
    int d = dl + it * 32;
    int gcol = dd * 64 + d;
    int kv = gcol >> 7, drow = gcol & 127;
    short8 v;
#pragma unroll
    for (int k = 0; k < 8; ++k) v[k] = (short)tile[t8 + k][d];
    *(short8*)(vt + ((size_t)(b * NKV_ + kv) * HD_ + drow) * NT_ + t0 + t8) = v;
  }
}

// ---------------- bf16 GEMM: C(M,N) = A(M,K) * B(N,K)^T ----------------
// 128x128 tile, BK=32, 4 waves (2x2 of 64x64), global_load_lds staging,
// XOR-swizzled LDS so ds_read_b128 fragments are ~conflict-free.
template<int FOUT>
__global__ __launch_bounds__(256, 2)
void gemm128(const u16* __restrict__ A,
             const u16* __restrict__ B1, void* __restrict__ C1, int N1,
             const u16* __restrict__ B2, void* __restrict__ C2, int N2,
             int bxsplit, int K)
{
  __shared__ u16 As[128 * 32];
  __shared__ u16 Bs[128 * 32];
  int bx = blockIdx.x;
  const int by = blockIdx.y;
  const u16* Bmat = B1; void* Cmat = C1; int N = N1;
  if (bx >= bxsplit) { Bmat = B2; Cmat = C2; N = N2; bx -= bxsplit; }
  const int m0 = by * 128, n0 = bx * 128;
  const int tid = threadIdx.x;
  const int wave = tid >> 6, lane = tid & 63;
  const int quad = lane >> 4, l15 = lane & 15;
  const int wm = wave >> 1, wn = wave & 1;

  // staging decode: chunk = 64 granules(16B) = 16 rows x 32cols; swizzle:
  // lds granule for (row m, k-granule g): (m>>1)*8 + (m&1)*4 + (g ^ ((m>>1)&3))
  const int p_local = lane >> 3;
  const int s7 = lane & 7;
  const int mlo = s7 >> 2;
  const int gg = (s7 & 3) ^ (p_local & 3);
  const int rowc = p_local * 2 + mlo;
  const int kel = gg * 8;

  const u16* Ag[2]; const u16* Bg[2];
  u16* Al[2]; u16* Bl[2];
#pragma unroll
  for (int q = 0; q < 2; ++q) {
    const int c = wave * 2 + q;
    Ag[q] = A    + (size_t)(m0 + c * 16 + rowc) * K + kel;
    Bg[q] = Bmat + (size_t)(n0 + c * 16 + rowc) * K + kel;
    Al[q] = As + c * 512;
    Bl[q] = Bs + c * 512;
  }

  f32x4 acc[4][4] = {};

  int a_addr[4], b_addr[4];
#pragma unroll
  for (int i = 0; i < 4; ++i) {
    int m = wm * 64 + i * 16 + l15;
    a_addr[i] = ((m >> 1) * 8 + (m & 1) * 4 + (quad ^ ((m >> 1) & 3))) * 8;
    int n = wn * 64 + i * 16 + l15;
    b_addr[i] = ((n >> 1) * 8 + (n & 1) * 4 + (quad ^ ((n >> 1) & 3))) * 8;
  }

  for (int k0 = 0; k0 < K; k0 += 32) {
#pragma unroll
    for (int q = 0; q < 2; ++q) {
      async_ld16(Ag[q] + k0, Al[q]);
      async_ld16(Bg[q] + k0, Bl[q]);
    }
    __syncthreads();
    short8 af[4], bf[4];
#pragma unroll
    for (int i = 0; i < 4; ++i) af[i] = *(const short8*)(As + a_addr[i]);
#pragma unroll
    for (int i = 0; i < 4; ++i) bf[i] = *(const short8*)(Bs + b_addr[i]);
#pragma unroll
    for (int mb = 0; mb < 4; ++mb)
#pragma unroll
      for (int nb = 0; nb < 4; ++nb)
        acc[mb][nb] = __builtin_amdgcn_mfma_f32_16x16x32_bf16(af[mb], bf[nb], acc[mb][nb], 0, 0, 0);
    __syncthreads();
  }

#pragma unroll
  for (int mb = 0; mb < 4; ++mb)
#pragma unroll
    for (int nb = 0; nb < 4; ++nb) {
      const int gn = n0 + wn * 64 + nb * 16 + l15;
#pragma unroll
      for (int r = 0; r < 4; ++r) {
        const int gm = m0 + wm * 64 + mb * 16 + quad * 4 + r;
        const float v = acc[mb][nb][r];
        if (FOUT) ((float*)Cmat)[(size_t)gm * N + gn] = v;
        else      ((u16*)Cmat)[(size_t)gm * N + gn] = f2b(v);
      }
    }
}

// ---------------- flash attention ----------------
// grid (qt=32, h=16, b=2), 256 thr = 4 waves x 16 Q-rows; K/V tiles of 64.
__global__ __launch_bounds__(256, 2)
void attn_kernel(const u16* __restrict__ Q, const u16* __restrict__ Kg,
                 const u16* __restrict__ Vt, u16* __restrict__ O)
{
  __shared__ u16 Ks[64 * 128];   // swizzled (T x D)
  __shared__ u16 Vs[128 * 64];   // swizzled (D x T)
  __shared__ u16 Ps[4 * 16 * 72];
  const int qt = blockIdx.x;
  const int h  = blockIdx.y;
  const int b  = blockIdx.z;
  const int kv = h >> 2;
  const int tid = threadIdx.x;
  const int wave = tid >> 6, lane = tid & 63;
  const int quad = lane >> 4, l15 = lane & 15;

  short8 qf[4];
  {
    const u16* qb = Q + ((size_t)(b * NH_ + h) * NT_ + qt * 64 + wave * 16 + l15) * HD_ + quad * 8;
#pragma unroll
    for (int kb = 0; kb < 4; ++kb) qf[kb] = *(const short8*)(qb + kb * 32);
  }
  const u16* Kbase = Kg + (size_t)(b * NKV_ + kv) * NT_ * HD_;
  const u16* Vbase = Vt + (size_t)(b * NKV_ + kv) * HD_ * NT_;

  const int krow = lane >> 4, kgs = lane & 15;
  const int vrow = lane >> 3, vgs = lane & 7;

  f32x4 acc_o[8] = {};
  float mrow[4] = {-INFINITY, -INFINITY, -INFINITY, -INFINITY};
  float lrow[4] = {0.f, 0.f, 0.f, 0.f};
  const float scale = 0.08838834764831845f;  // 1/sqrt(128)
  u16* Pw = Ps + wave * (16 * 72);

  for (int kt = 0; kt <= qt; ++kt) {
#pragma unroll
    for (int q = 0; q < 4; ++q) {
      const int c = wave * 4 + q;
      const int rk = c * 4 + krow;
      const int gk = kgs ^ (rk & 7);
      async_ld16(Kbase + (size_t)(kt * 64 + rk) * HD_ + gk * 8, Ks + c * 512);
      const int rv = c * 8 + vrow;
      const int gv = vgs ^ (rv & 7);
      async_ld16(Vbase + (size_t)rv * NT_ + kt * 64 + gv * 8, Vs + c * 512);
    }
    __syncthreads();

    // S = Q K^T   (wave: 16 rows x 64 cols)
    f32x4 S[4] = {};
#pragma unroll
    for (int nb = 0; nb < 4; ++nb) {
      const int row = nb * 16 + l15;
#pragma unroll
      for (int kb = 0; kb < 4; ++kb) {
        const int g = kb * 4 + quad;
        short8 kf = *(const short8*)(Ks + row * 128 + (g ^ (row & 7)) * 8);
        S[nb] = __builtin_amdgcn_mfma_f32_16x16x32_bf16(qf[kb], kf, S[nb], 0, 0, 0);
      }
    }

    const int qrow0 = qt * 64 + wave * 16 + quad * 4;
#pragma unroll
    for (int nb = 0; nb < 4; ++nb) {
      const int kc = kt * 64 + nb * 16 + l15;
#pragma unroll
      for (int r = 0; r < 4; ++r) {
        float sv = S[nb][r] * scale;
        if (kt == qt && kc > qrow0 + r) sv = -INFINITY;
        S[nb][r] = sv;
      }
    }

    // online softmax; rows live in quad-groups of 16 lanes
    float mx[4];
#pragma unroll
    for (int r = 0; r < 4; ++r)
      mx[r] = fmaxf(fmaxf(S[0][r], S[1][r]), fmaxf(S[2][r], S[3][r]));
#pragma unroll
    for (int off = 1; off < 16; off <<= 1) {
#pragma unroll
      for (int r = 0; r < 4; ++r) mx[r] = fmaxf(mx[r], __shfl_xor(mx[r], off));
    }
    float alpha[4], rs[4];
#pragma unroll
    for (int r = 0; r < 4; ++r) {
      float mn = fmaxf(mrow[r], mx[r]);
      alpha[r] = __expf(mrow[r] - mn);
      mrow[r] = mn;
      rs[r] = 0.f;
    }
#pragma unroll
    for (int nb = 0; nb < 4; ++nb)
#pragma unroll
      for (int r = 0; r < 4; ++r) {
        float p = __expf(S[nb][r] - mrow[r]);
        S[nb][r] = p;
        rs[r] += p;
      }
#pragma unroll
    for (int off = 1; off < 16; off <<= 1) {
#pragma unroll
      for (int r = 0; r < 4; ++r) rs[r] += __shfl_xor(rs[r], off);
    }
#pragma unroll
    for (int r = 0; r < 4; ++r) lrow[r] = lrow[r] * alpha[r] + rs[r];
#pragma unroll
    for (int db = 0; db < 8; ++db)
#pragma unroll
      for (int r = 0; r < 4; ++r) acc_o[db][r] *= alpha[r];

    // P: C-layout -> A-layout via wave-private LDS round-trip
#pragma unroll
    for (int nb = 0; nb < 4; ++nb)
#pragma unroll
      for (int r = 0; r < 4; ++r)
        Pw[(quad * 4 + r) * 72 + nb * 16 + l15] = f2b(S[nb][r]);

    short8 pf[2];
#pragma unroll
    for (int k2 = 0; k2 < 2; ++k2)
      pf[k2] = *(const short8*)(Pw + l15 * 72 + k2 * 32 + quad * 8);

    // O += P V
#pragma unroll
    for (int db = 0; db < 8; ++db) {
      const int row = db * 16 + l15;
#pragma unroll
      for (int k2 = 0; k2 < 2; ++k2) {
        const int g = k2 * 4 + quad;
        short8 vf = *(const short8*)(Vs + row * 64 + (g ^ (row & 7)) * 8);
        acc_o[db] = __builtin_amdgcn_mfma_f32_16x16x32_bf16(pf[k2], vf, acc_o[db], 0, 0, 0);
      }
    }
    __syncthreads();
  }

  const size_t orow = ((size_t)b * NT_ + qt * 64 + wave * 16) * (NH_ * HD_);
  float inv[4];
#pragma unroll
  for (int r = 0; r < 4; ++r) inv[r] = 1.f / lrow[r];
#pragma unroll
  for (int db = 0; db < 8; ++db)
#pragma unroll
    for (int r = 0; r < 4; ++r)
      O[orow + (size_t)(quad * 4 + r) * (NH_ * HD_) + h * HD_ + db * 16 + l15] =
          f2b(acc_o[db][r] * inv[r]);
}

extern "C" void kernel_launch(void* const* d_in, const int* in_sizes, int n_in,
                              void* d_out, int out_size, void* d_ws, size_t ws_size,
                              hipStream_t stream) {
  const float* x  = (const float*)d_in[0];
  const float* Wq = (const float*)d_in[1];
  const float* Wk = (const float*)d_in[2];
  const float* Wv = (const float*)d_in[3];
  const float* Wo = (const float*)d_in[4];
  float* out = (float*)d_out;
  char* ws = (char*)d_ws;
  const size_t MB = (size_t)1 << 20;
  u16* xb   = (u16*)(ws + 0);        // 16MB (x bf16); reused later for attention O
  u16* wqb  = (u16*)(ws + 16 * MB);  // 8MB
  u16* wkb  = (u16*)(ws + 24 * MB);  // 2MB
  u16* wvb  = (u16*)(ws + 26 * MB);  // 2MB
  u16* wob  = (u16*)(ws + 28 * MB);  // 8MB
  u16* qraw = (u16*)(ws + 36 * MB);  // 16MB
  u16* kraw = (u16*)(ws + 52 * MB);  // 4MB
  u16* vraw = (u16*)(ws + 56 * MB);  // 4MB
  u16* Qr   = (u16*)(ws + 60 * MB);  // 16MB
  u16* Kr   = (u16*)(ws + 76 * MB);  // 4MB
  u16* Vtb  = (u16*)(ws + 80 * MB);  // 4MB  (end: 84MB)
  u16* Ob   = xb;                    // alias: x bf16 dead after projections

  f2bf_kernel<<<8192, 256, 0, stream>>>(x,  xb,  NM_ * NC_ / 4);
  f2bf_kernel<<<4096, 256, 0, stream>>>(Wq, wqb, 2048 * 2048 / 4);
  f2bf_kernel<<<1024, 256, 0, stream>>>(Wk, wkb, 512 * 2048 / 4);
  f2bf_kernel<<<1024, 256, 0, stream>>>(Wv, wvb, 512 * 2048 / 4);
  f2bf_kernel<<<4096, 256, 0, stream>>>(Wo, wob, 2048 * 2048 / 4);

  // Q projection (N=2048), then K+V fused in one launch (split grid)
  gemm128<0><<<dim3(16, 32), 256, 0, stream>>>(xb, wqb, qraw, 2048, wqb, qraw, 2048, 16, 2048);
  gemm128<0><<<dim3(8, 32), 256, 0, stream>>>(xb, wkb, kraw, 512, wvb, vraw, 512, 4, 2048);

  rope_reshape<<<16384, 256, 0, stream>>>(qraw, Qr, NH_);
  rope_reshape<<<4096, 256, 0, stream>>>(kraw, Kr, NKV_);
  vtrans<<<dim3(64, 8), 256, 0, stream>>>(vraw, Vtb);

  attn_kernel<<<dim3(32, 16, 2), 256, 0, stream>>>(Qr, Kr, Vtb, Ob);

  // out = O @ Wo^T, fp32 epilogue
  gemm128<1><<<dim3(16, 32), 256, 0, stream>>>(Ob, wob, out, 2048, wob, out, 2048, 16, 2048);
}

// Round 2
// 301.658 us; speedup vs baseline: 1.5148x; 1.5148x over previous
//
#include <hip/hip_runtime.h>
#include <stdint.h>

typedef unsigned short u16;
typedef __attribute__((ext_vector_type(8))) short short8;
typedef __attribute__((ext_vector_type(4))) short short4v;
typedef __attribute__((ext_vector_type(4))) float f32x4;

#define NB_  2
#define NT_  2048
#define NC_  2048
#define NH_  16
#define NKV_ 4
#define HD_  128
#define NM_  (NB_*NT_)   // 4096

__device__ __forceinline__ u16 f2b(float x) {
  uint32_t u = __float_as_uint(x);
  u += 0x7fffu + ((u >> 16) & 1u);   // RNE
  return (u16)(u >> 16);
}
__device__ __forceinline__ float b2f(u16 x) {
  return __uint_as_float(((uint32_t)x) << 16);
}
__device__ __forceinline__ uint32_t pk2(float a, float b) {
  return (uint32_t)f2b(a) | ((uint32_t)f2b(b) << 16);
}

typedef __attribute__((address_space(1))) uint32_t* gp1_t;
typedef __attribute__((address_space(3))) uint32_t* lp3_t;
__device__ __forceinline__ void async_ld16(const void* g, void* l) {
  __builtin_amdgcn_global_load_lds((gp1_t)(uintptr_t)g, (lp3_t)(uintptr_t)l, 16, 0, 0);
}

// ---------------- fused fp32 -> bf16 convert (all 5 tensors, 1 launch) ----------------
__global__ void f2bf_all(const float* __restrict__ x,  const float* __restrict__ wq,
                         const float* __restrict__ wk, const float* __restrict__ wv,
                         const float* __restrict__ wo,
                         u16* xb, u16* wqb, u16* wkb, u16* wvb, u16* wob) {
  int bid = blockIdx.x;
  const float* src; u16* dst; int base;
  if      (bid < 8192)  { src = x;  dst = xb;  base = bid; }
  else if (bid < 12288) { src = wq; dst = wqb; base = bid - 8192; }
  else if (bid < 13312) { src = wk; dst = wkb; base = bid - 12288; }
  else if (bid < 14336) { src = wv; dst = wvb; base = bid - 13312; }
  else                  { src = wo; dst = wob; base = bid - 14336; }
  int i = base * 256 + threadIdx.x;
  const float4 v = ((const float4*)src)[i];
  short4v o;
  o[0] = (short)f2b(v.x); o[1] = (short)f2b(v.y);
  o[2] = (short)f2b(v.z); o[3] = (short)f2b(v.w);
  *(short4v*)(dst + (size_t)i * 4) = o;
}

// ---------------- fused post-proj: Q-rope | K-rope | V-transpose ----------------
__global__ void postk(const u16* __restrict__ qraw, const u16* __restrict__ kraw,
                      const u16* __restrict__ vraw,
                      u16* __restrict__ Qr, u16* __restrict__ Kr, u16* __restrict__ Vt) {
  __shared__ u16 tile[64][72];
  int bid = blockIdx.x;
  if (bid < 20480) {
    const u16* raw; u16* out; int nheads; int tid;
    if (bid < 16384) { raw = qraw; out = Qr; nheads = NH_;  tid = bid * 256 + threadIdx.x; }
    else             { raw = kraw; out = Kr; nheads = NKV_; tid = (bid - 16384) * 256 + threadIdx.x; }
    int j = tid & 63;
    int t = (tid >> 6) & (NT_ - 1);
    int bh = tid >> 17;
    int h = bh % nheads, b = bh / nheads;
    const u16* src = raw + ((size_t)(b * NT_ + t) * nheads + h) * HD_;
    float q0 = b2f(src[j]), q1 = b2f(src[j + 64]);
    float inv = expf(-0.14391156831212787f * (float)j);  // ln(10000)/64
    float ang = (float)t * inv;
    float c = cosf(ang), s = sinf(ang);
    u16* dst = out + ((size_t)(b * nheads + h) * NT_ + t) * HD_;
    dst[j]      = f2b(q0 * c - q1 * s);
    dst[j + 64] = f2b(q1 * c + q0 * s);
  } else {
    int idx = bid - 20480;            // 0..511
    int tt = idx & 63, dd = idx >> 6; // 64 t-tiles x 8 d-tiles
    int tid = threadIdx.x;
    int r = tid >> 3, c8 = (tid & 7) * 8;
#pragma unroll
    for (int it = 0; it < 2; ++it) {
      int row = r + it * 32;
      short8 v = *(const short8*)(vraw + (size_t)(tt * 64 + row) * (NKV_ * HD_) + dd * 64 + c8);
      *(short8*)(&tile[row][c8]) = v;
    }
    __syncthreads();
    int b = (tt * 64) >> 11, t0 = (tt * 64) & (NT_ - 1);
    int dl = tid >> 3, t8 = (tid & 7) * 8;
#pragma unroll
    for (int it = 0; it < 2; ++it) {
      int d = dl + it * 32;
      int gcol = dd * 64 + d;
      int kv = gcol >> 7, drow = gcol & 127;
      short8 v;
#pragma unroll
      for (int k = 0; k < 8; ++k) v[k] = (short)tile[t8 + k][d];
      *(short8*)(Vt + ((size_t)(b * NKV_ + kv) * HD_ + drow) * NT_ + t0 + t8) = v;
    }
  }
}

// ---------------- bf16 GEMM: C(M,N) = A(M,K) * B(N,K)^T ----------------
// 128x128 tile, BK=32, single-barrier double-buffered global_load_lds staging.
template<int FOUT>
__global__ __launch_bounds__(256, 2)
void gemm128(const u16* __restrict__ A,
             const u16* __restrict__ B1, void* __restrict__ C1, int N1,
             const u16* __restrict__ B2, void* __restrict__ C2, int N2,
             const u16* __restrict__ B3, void* __restrict__ C3, int N3,
             int s1, int s2, int K)
{
  __shared__ u16 As[2 * 128 * 32];
  __shared__ u16 Bs[2 * 128 * 32];
  int bx = blockIdx.x;
  const int by = blockIdx.y;
  const u16* Bmat; void* Cmat; int N;
  if      (bx < s1) { Bmat = B1; Cmat = C1; N = N1; }
  else if (bx < s2) { Bmat = B2; Cmat = C2; N = N2; bx -= s1; }
  else              { Bmat = B3; Cmat = C3; N = N3; bx -= s2; }
  const int m0 = by * 128, n0 = bx * 128;
  const int tid = threadIdx.x;
  const int wave = tid >> 6, lane = tid & 63;
  const int quad = lane >> 4, l15 = lane & 15;
  const int wm = wave >> 1, wn = wave & 1;

  const int p_local = lane >> 3;
  const int s7 = lane & 7;
  const int mlo = s7 >> 2;
  const int gg = (s7 & 3) ^ (p_local & 3);
  const int rowc = p_local * 2 + mlo;
  const int kel = gg * 8;

  const u16* Ag[2]; const u16* Bg[2];
  u16* Al[2]; u16* Bl[2];
#pragma unroll
  for (int q = 0; q < 2; ++q) {
    const int c = wave * 2 + q;
    Ag[q] = A    + (size_t)(m0 + c * 16 + rowc) * K + kel;
    Bg[q] = Bmat + (size_t)(n0 + c * 16 + rowc) * K + kel;
    Al[q] = As + c * 512;
    Bl[q] = Bs + c * 512;
  }

  f32x4 acc[4][4] = {};

  int a_addr[4], b_addr[4];
#pragma unroll
  for (int i = 0; i < 4; ++i) {
    int m = wm * 64 + i * 16 + l15;
    a_addr[i] = ((m >> 1) * 8 + (m & 1) * 4 + (quad ^ ((m >> 1) & 3))) * 8;
    int n = wn * 64 + i * 16 + l15;
    b_addr[i] = ((n >> 1) * 8 + (n & 1) * 4 + (quad ^ ((n >> 1) & 3))) * 8;
  }

  const int nk = K >> 5;
  // prologue: stage tile 0 into buffer 0
#pragma unroll
  for (int q = 0; q < 2; ++q) {
    async_ld16(Ag[q], Al[q]);
    async_ld16(Bg[q], Bl[q]);
  }

  for (int i = 0; i < nk; ++i) {
    __syncthreads();   // drains tile i's loads; all waves done reading other buf
    if (i + 1 < nk) {
      const int off = ((i + 1) & 1) * 4096;
      const int k0 = (i + 1) << 5;
#pragma unroll
      for (int q = 0; q < 2; ++q) {
        async_ld16(Ag[q] + k0, Al[q] + off);
        async_ld16(Bg[q] + k0, Bl[q] + off);
      }
    }
    const int off = (i & 1) * 4096;
    short8 af[4], bf[4];
#pragma unroll
    for (int j = 0; j < 4; ++j) af[j] = *(const short8*)(As + off + a_addr[j]);
#pragma unroll
    for (int j = 0; j < 4; ++j) bf[j] = *(const short8*)(Bs + off + b_addr[j]);
#pragma unroll
    for (int mb = 0; mb < 4; ++mb)
#pragma unroll
      for (int nb = 0; nb < 4; ++nb)
        acc[mb][nb] = __builtin_amdgcn_mfma_f32_16x16x32_bf16(af[mb], bf[nb], acc[mb][nb], 0, 0, 0);
  }

#pragma unroll
  for (int mb = 0; mb < 4; ++mb)
#pragma unroll
    for (int nb = 0; nb < 4; ++nb) {
      const int gn = n0 + wn * 64 + nb * 16 + l15;
#pragma unroll
      for (int r = 0; r < 4; ++r) {
        const int gm = m0 + wm * 64 + mb * 16 + quad * 4 + r;
        const float v = acc[mb][nb][r];
        if (FOUT) ((float*)Cmat)[(size_t)gm * N + gn] = v;
        else      ((u16*)Cmat)[(size_t)gm * N + gn] = f2b(v);
      }
    }
}

// ---------------- flash attention (S^T formulation, dbuf, pair-balanced) ----------------
// grid (pid=16, h=16, b=2); block = 4 waves x 16 Q-rows; handles qt = pid and qt = 31-pid.
__global__ __launch_bounds__(256, 2)
void attn_kernel(const u16* __restrict__ Q, const u16* __restrict__ Kg,
                 const u16* __restrict__ Vt, u16* __restrict__ O)
{
  __shared__ u16 Ks[2 * 64 * 128];
  __shared__ u16 Vs[2 * 128 * 64];
  const int pid = blockIdx.x;
  const int h  = blockIdx.y;
  const int b  = blockIdx.z;
  const int kv = h >> 2;
  const int tid = threadIdx.x;
  const int wave = tid >> 6, lane = tid & 63;
  const int quad = lane >> 4, l15 = lane & 15;

  const u16* Kbase = Kg + (size_t)(b * NKV_ + kv) * NT_ * HD_;
  const u16* Vbase = Vt + (size_t)(b * NKV_ + kv) * HD_ * NT_;

  const int krow = lane >> 4, kgs = lane & 15;
  const int vrow = lane >> 3, vgs = lane & 7;
  const float scale = 0.08838834764831845f;  // 1/sqrt(128)

  // stage K/V tile kt into buffer pbuf
  auto stage = [&](int kt, int pbuf) {
    u16* KsB = Ks + pbuf * 8192;
    u16* VsB = Vs + pbuf * 8192;
#pragma unroll
    for (int q = 0; q < 4; ++q) {
      const int c = wave * 4 + q;
      const int rk = c * 4 + krow;
      const int gk = kgs ^ (rk & 7);
      async_ld16(Kbase + (size_t)(kt * 64 + rk) * HD_ + gk * 8, KsB + c * 512);
      const int rv = c * 8 + vrow;
      const int gv = vgs ^ (rv & 7);
      async_ld16(Vbase + (size_t)rv * NT_ + kt * 64 + gv * 8, VsB + c * 512);
    }
  };

  stage(0, 0);   // prologue
  int g = 0;     // global tile counter -> buffer parity

  for (int phase = 0; phase < 2; ++phase) {
    const int qt = phase ? (31 - pid) : pid;

    short8 qf[4];
    {
      const u16* qb = Q + ((size_t)(b * NH_ + h) * NT_ + qt * 64 + wave * 16 + l15) * HD_ + quad * 8;
#pragma unroll
      for (int kb = 0; kb < 4; ++kb) qf[kb] = *(const short8*)(qb + kb * 32);
    }

    f32x4 acc_o[8] = {};
    float m_st = -INFINITY, l_st = 0.f;
    const int tg = qt * 64 + wave * 16 + l15;  // this lane's Q row (dup x4 across quads)

    for (int kt = 0; kt <= qt; ++kt) {
      __syncthreads();   // tile g's loads drained; other buf free
      const bool have_next = (kt < qt) || (phase == 0);
      if (have_next) stage((kt < qt) ? kt + 1 : 0, (g + 1) & 1);

      const u16* KsB = Ks + (g & 1) * 8192;
      const u16* VsB = Vs + (g & 1) * 8192;

      // S^T = K Q^T : lane holds S[t = l15][s = nb*16 + quad*4 + r]
      f32x4 S[4] = {};
#pragma unroll
      for (int nb = 0; nb < 4; ++nb) {
        const int row = nb * 16 + l15;
#pragma unroll
        for (int kb = 0; kb < 4; ++kb) {
          const int gi = kb * 4 + quad;
          short8 kf = *(const short8*)(KsB + row * 128 + (gi ^ (row & 7)) * 8);
          S[nb] = __builtin_amdgcn_mfma_f32_16x16x32_bf16(kf, qf[kb], S[nb], 0, 0, 0);
        }
      }

      if (kt == qt) {   // wave-uniform branch: mask only on diagonal tile
#pragma unroll
        for (int nb = 0; nb < 4; ++nb)
#pragma unroll
          for (int r = 0; r < 4; ++r) {
            const int sg = kt * 64 + nb * 16 + quad * 4 + r;
            S[nb][r] = (sg > tg) ? -INFINITY : S[nb][r] * scale;
          }
      } else {
#pragma unroll
        for (int nb = 0; nb < 4; ++nb)
#pragma unroll
          for (int r = 0; r < 4; ++r) S[nb][r] *= scale;
      }

      // online softmax: each lane owns row t=l15 (duplicated across 4 quads)
      float mx = -INFINITY;
#pragma unroll
      for (int nb = 0; nb < 4; ++nb)
#pragma unroll
        for (int r = 0; r < 4; ++r) mx = fmaxf(mx, S[nb][r]);
      mx = fmaxf(mx, __shfl_xor(mx, 16));
      mx = fmaxf(mx, __shfl_xor(mx, 32));
      const float mn = fmaxf(m_st, mx);
      const float alpha_t = __expf(m_st - mn);
      m_st = mn;
      float rs = 0.f;
#pragma unroll
      for (int nb = 0; nb < 4; ++nb)
#pragma unroll
        for (int r = 0; r < 4; ++r) {
          const float p = __expf(S[nb][r] - mn);
          S[nb][r] = p;
          rs += p;
        }
      rs += __shfl_xor(rs, 16);
      rs += __shfl_xor(rs, 32);
      l_st = l_st * alpha_t + rs;

      // rescale O accumulator: rows = quad*4+r, alpha held at lane (quad*4+r)
      float alpha_r[4];
#pragma unroll
      for (int r = 0; r < 4; ++r) alpha_r[r] = __shfl(alpha_t, quad * 4 + r);
#pragma unroll
      for (int db = 0; db < 8; ++db)
#pragma unroll
        for (int r = 0; r < 4; ++r) acc_o[db][r] *= alpha_r[r];

      // P: S^T C-layout -> A-layout via pack + shuffles (no LDS)
      uint32_t d0[4], d1[4];
#pragma unroll
      for (int nb = 0; nb < 4; ++nb) {
        d0[nb] = pk2(S[nb][0], S[nb][1]);
        d1[nb] = pk2(S[nb][2], S[nb][3]);
      }
      const int srcA = ((quad & 1) * 2) * 16 + l15;
      const int srcB = srcA + 16;
      const bool hi = quad >= 2;
      short8 pf[2];
#pragma unroll
      for (int k2 = 0; k2 < 2; ++k2) {
        const int nbL = k2 * 2, nbH = k2 * 2 + 1;
        uint32_t a0 = (uint32_t)__shfl((int)d0[nbL], srcA);
        uint32_t a1 = (uint32_t)__shfl((int)d1[nbL], srcA);
        uint32_t a2 = (uint32_t)__shfl((int)d0[nbL], srcB);
        uint32_t a3 = (uint32_t)__shfl((int)d1[nbL], srcB);
        uint32_t b0 = (uint32_t)__shfl((int)d0[nbH], srcA);
        uint32_t b1 = (uint32_t)__shfl((int)d1[nbH], srcA);
        uint32_t b2 = (uint32_t)__shfl((int)d0[nbH], srcB);
        uint32_t b3 = (uint32_t)__shfl((int)d1[nbH], srcB);
        uint32_t w[4] = { hi ? b0 : a0, hi ? b1 : a1, hi ? b2 : a2, hi ? b3 : a3 };
        pf[k2] = *(short8*)w;
      }

      // O += P V
#pragma unroll
      for (int db = 0; db < 8; ++db) {
        const int row = db * 16 + l15;
#pragma unroll
        for (int k2 = 0; k2 < 2; ++k2) {
          const int gi = k2 * 4 + quad;
          short8 vf = *(const short8*)(VsB + row * 64 + (gi ^ (row & 7)) * 8);
          acc_o[db] = __builtin_amdgcn_mfma_f32_16x16x32_bf16(pf[k2], vf, acc_o[db], 0, 0, 0);
        }
      }
      ++g;
    }

    // epilogue: rows = quad*4+r, 1/l held at lane (quad*4+r)
    const float linv = 1.f / l_st;
    float inv_r[4];
#pragma unroll
    for (int r = 0; r < 4; ++r) inv_r[r] = __shfl(linv, quad * 4 + r);
    const size_t orow = ((size_t)b * NT_ + qt * 64 + wave * 16) * (NH_ * HD_);
#pragma unroll
    for (int db = 0; db < 8; ++db)
#pragma unroll
      for (int r = 0; r < 4; ++r)
        O[orow + (size_t)(quad * 4 + r) * (NH_ * HD_) + h * HD_ + db * 16 + l15] =
            f2b(acc_o[db][r] * inv_r[r]);
  }
}

extern "C" void kernel_launch(void* const* d_in, const int* in_sizes, int n_in,
                              void* d_out, int out_size, void* d_ws, size_t ws_size,
                              hipStream_t stream) {
  const float* x  = (const float*)d_in[0];
  const float* Wq = (const float*)d_in[1];
  const float* Wk = (const float*)d_in[2];
  const float* Wv = (const float*)d_in[3];
  const float* Wo = (const float*)d_in[4];
  float* out = (float*)d_out;
  char* ws = (char*)d_ws;
  const size_t MB = (size_t)1 << 20;
  u16* xb   = (u16*)(ws + 0);        // 16MB; reused later as attention O
  u16* wqb  = (u16*)(ws + 16 * MB);  // 8MB
  u16* wkb  = (u16*)(ws + 24 * MB);  // 2MB
  u16* wvb  = (u16*)(ws + 26 * MB);  // 2MB
  u16* wob  = (u16*)(ws + 28 * MB);  // 8MB
  u16* qraw = (u16*)(ws + 36 * MB);  // 16MB
  u16* kraw = (u16*)(ws + 52 * MB);  // 4MB
  u16* vraw = (u16*)(ws + 56 * MB);  // 4MB
  u16* Qr   = (u16*)(ws + 60 * MB);  // 16MB
  u16* Kr   = (u16*)(ws + 76 * MB);  // 4MB
  u16* Vtb  = (u16*)(ws + 80 * MB);  // 4MB (end 84MB)
  u16* Ob   = xb;

  f2bf_all<<<18432, 256, 0, stream>>>(x, Wq, Wk, Wv, Wo, xb, wqb, wkb, wvb, wob);

  // fused QKV projection: bx 0..15 -> Q(N=2048), 16..19 -> K(512), 20..23 -> V(512)
  gemm128<0><<<dim3(24, 32), 256, 0, stream>>>(xb, wqb, qraw, 2048,
                                               wkb, kraw, 512,
                                               wvb, vraw, 512, 16, 20, 2048);

  postk<<<20992, 256, 0, stream>>>(qraw, kraw, vraw, Qr, Kr, Vtb);

  attn_kernel<<<dim3(16, 16, 2), 256, 0, stream>>>(Qr, Kr, Vtb, Ob);

  gemm128<1><<<dim3(16, 32), 256, 0, stream>>>(Ob, wob, out, 2048,
                                               wob, out, 2048,
                                               wob, out, 2048, 16, 32, 2048);
}